// Round 13
// baseline (599.671 us; speedup 1.0000x reference)
//
#include <hip/hip_runtime.h>
#include <math.h>

// Problem constants (from reference setup_inputs)
#define B      2
#define C      128     // channels
#define H      256     // d_model == image height
#define W      512     // image width
#define NCOND  512
#define DCOND  512
#define DATTN  256
#define KKEEP  204     // int(256 * (1 - 0.2))

// Workspace layout (byte offsets). Total ~136.4 MB.
#define WS_CATN   0ull          // [B][256][514][256] bf16 = 134742016 B
#define WS_KQ     134742016ull  // kqc  [2][8][256][64]     524288 B (pb aliases after attn)
#define WS_VOT    135266304ull  // voc  [2][8][256][64]     524288 B
#define WS_W9     135790592ull  // bf16 w9p [36][128co][64] 589824 B (16KB per (c,p), preswizzled)
#define WS_BIN    136380416ull  // f32 binary[256]          1024 B
#define WS_ST2    136381440ull  // f32 stats [B][32][2]     512 B

typedef __attribute__((ext_vector_type(8))) short bf16x8;
typedef __attribute__((ext_vector_type(4))) float f32x4;

union U8 { bf16x8 v; ushort u[8]; };

__device__ inline ushort f2bf(float f) {
    union { float f; unsigned u; } v; v.f = f;
    unsigned r = v.u + 0x7fffu + ((v.u >> 16) & 1u);   // RNE
    return (ushort)(r >> 16);
}

// Direct global->LDS async copy, 16 B/lane (dest = uniform base + lane*16).
__device__ __forceinline__ void gld16(const ushort* g, void* l) {
    __builtin_amdgcn_global_load_lds(
        (const __attribute__((address_space(1))) unsigned int*)(const void*)g,
        (__attribute__((address_space(3))) unsigned int*)l, 16, 0, 0);
}

// Bijective XCD-contiguous block remap (grid % 8 == 0).
__device__ __forceinline__ int xcdswz(int bid, int per) {
    return (bid & 7) * per + (bid >> 3);
}

// ---------------------------------------------------------------------------
// Learned mask: binary[h] = 1 iff sigmoid(mask_w[h]) is among the top-204.
__global__ void k_binary(const float* __restrict__ mask_w, float* __restrict__ bin) {
    __shared__ float s[H];
    int t = threadIdx.x;
    float sv = 1.0f / (1.0f + __expf(-mask_w[t]));
    s[t] = sv;
    __syncthreads();
    int cnt = 0;
    for (int j = 0; j < H; ++j) cnt += (s[j] > sv) ? 1 : 0;
    bin[t] = (cnt < KKEEP) ? 1.0f : 0.0f;
}

__global__ void k_maskout(const float* __restrict__ bin, float* __restrict__ mout) {
    int i = blockIdx.x * 256 + threadIdx.x;
    if (i < B * W * H) mout[i] = bin[i & (H - 1)];
}

// ---------------------------------------------------------------------------
// K/V projection + weight folding (associativity):
//   kq[b][n][h]  = sum_d (v.Wk)[n,d] * Wq[h,d]   (S = X @ kq^T)
//   vo[b][n][h]  = sum_d (v.Wv)[n,d] * Wo[d,h]   (out = P @ vo)
// Outputs written in the stage-chunked, pre-swizzled layouts k_attn stages.
__launch_bounds__(256)
__global__ void k_kv(const float* __restrict__ v, const float* __restrict__ Wk,
                     const float* __restrict__ Wv, const float* __restrict__ Wq,
                     const float* __restrict__ Wo, ushort* __restrict__ kqc,
                     ushort* __restrict__ voc) {
    __shared__ float vrow[DCOND];
    __shared__ float kld[DATTN];
    __shared__ float vld[DATTN];
    int bn = blockIdx.x;              // b*NCOND + n
    int t  = threadIdx.x;
    const float* vp = v + (size_t)bn * DCOND;
    for (int i = t; i < DCOND; i += 256) vrow[i] = vp[i];
    __syncthreads();
    float ka = 0.f, va = 0.f;
    for (int d4 = 0; d4 < DCOND / 4; ++d4) {
        float4 vv = *(const float4*)(vrow + d4 * 4);
        const float* wk = Wk + (d4 * 4) * DATTN + t;
        const float* wv = Wv + (d4 * 4) * DATTN + t;
        ka += vv.x * wk[0];         va += vv.x * wv[0];
        ka += vv.y * wk[DATTN];     va += vv.y * wv[DATTN];
        ka += vv.z * wk[2 * DATTN]; va += vv.z * wv[2 * DATTN];
        ka += vv.w * wk[3 * DATTN]; va += vv.w * wv[3 * DATTN];
    }
    kld[t] = ka; vld[t] = va;
    __syncthreads();
    float kq = 0.f;
    const float4* wqr = (const float4*)(Wq + (size_t)t * DATTN);
#pragma unroll 8
    for (int d4 = 0; d4 < DATTN / 4; ++d4) {
        float4 w = wqr[d4];
        kq += kld[d4 * 4] * w.x + kld[d4 * 4 + 1] * w.y
            + kld[d4 * 4 + 2] * w.z + kld[d4 * 4 + 3] * w.w;
    }
    float vo = 0.f;
#pragma unroll 8
    for (int d = 0; d < DATTN; ++d) vo += vld[d] * Wo[(size_t)d * 256 + t];

    int b = bn >> 9, n = bn & 511;
    // kqc: chunk s = (h>>6)*2 + (n>>8); row n&255 (128 B); unit u=(h>>3)&7 at slot u^(n&7)
    {
        int s    = ((t >> 6) << 1) | (n >> 8);
        int nl   = n & 255;
        int slot = (((t >> 3) & 7) ^ (n & 7));
        kqc[(((size_t)(b * 8 + s)) * 256 + nl) * 64 + slot * 8 + (t & 7)] = f2bf(kq);
    }
    // voc: chunk s2 = n>>6; row d=t (128 B); unit u=(n>>3)&7 at slot u^(d&7)
    {
        int s2   = n >> 6;
        int slot = (((n >> 3) & 7) ^ (t & 7));
        voc[(((size_t)(b * 8 + s2)) * 256 + t) * 64 + slot * 8 + (n & 7)] = f2bf(vo);
    }
}

// conv weights -> w9p[(c*9+p)][co][64 ush], pre-swizzled for LDS image:
// 16B unit slot us of row co holds logical unit us ^ (co&7).
__global__ void k_w9p(const float* __restrict__ cw, ushort* __restrict__ w9p) {
    int i = blockIdx.x * 256 + threadIdx.x;
    if (i >= 294912) return;          // 36 * 128 * 64
    int cp = i >> 13;                 // c*9 + p
    int r  = i & 8191;
    int co = r >> 6;
    int u  = r & 63;
    int us = u >> 3, j = u & 7;
    int c  = cp / 9, p = cp - c * 9;
    int cc = ((us ^ (co & 7)) << 3) | j;          // logical cc within chunk
    int ci = c * 64 + cc;
    w9p[(size_t)cp * 8192 + co * 64 + u] = f2bf(cw[(co * 256 + ci) * 9 + p]);
}

// ---------------------------------------------------------------------------
// Fused MFMA cross-attention, 2-GEMM form with async-staged B operands.
// Block = 32 rows (b, ci, w0..w0+31), 4 waves (round-9/10 proven structure).
// + XCD-contiguous block swizzle, + s_setprio around MFMA clusters (T5).
__launch_bounds__(256)
__global__ void k_attn(const float* __restrict__ x, const ushort* __restrict__ kqc,
                       const ushort* __restrict__ voc, const float* __restrict__ bo,
                       ushort* __restrict__ af16) {
    __shared__ __align__(16) char arena[33792];
    __shared__ __align__(16) char bbuf[32768];
    float* smax = (float*)(arena + 32768);
    float* ssum = (float*)(arena + 33280);

    const int t   = threadIdx.x;
    const int ln  = t & 63;
    const int blk = xcdswz(blockIdx.x, 512);     // 4096 blocks
    const int b   = blk >> 11;
    const int ci  = (blk >> 4) & 127;
    const int w0  = (blk & 15) << 5;
    const int wid = t >> 6;
    const int lr  = t & 15;
    const int lg  = (t & 63) >> 4;

    // ---- Phase 1: load X tile -> Xs[w][h] bf16 (thread t = h)
    {
        const float* xp = x + (((size_t)b * C + ci) * H + t) * W + w0;
#pragma unroll
        for (int j4 = 0; j4 < 8; ++j4) {
            float4 v4 = *(const float4*)(xp + j4 * 4);
            int j = j4 * 4;
            *(ushort*)(arena + (j + 0) * 512 + ((2 * t) ^ (((j + 0) & 7) << 4))) = f2bf(v4.x);
            *(ushort*)(arena + (j + 1) * 512 + ((2 * t) ^ (((j + 1) & 7) << 4))) = f2bf(v4.y);
            *(ushort*)(arena + (j + 2) * 512 + ((2 * t) ^ (((j + 2) & 7) << 4))) = f2bf(v4.z);
            *(ushort*)(arena + (j + 3) * 512 + ((2 * t) ^ (((j + 3) & 7) << 4))) = f2bf(v4.w);
        }
    }

    // ---- Phase 2: S = Xs @ kq^T, staged B.
    float rinv[2][4];
    {
        f32x4 sac[2][8];
#pragma unroll
        for (int mb = 0; mb < 2; ++mb)
#pragma unroll
            for (int g = 0; g < 8; ++g) sac[mb][g] = (f32x4){0.f, 0.f, 0.f, 0.f};
        const ushort* kqb = kqc + (size_t)b * 131072;
        for (int s = 0; s < 8; ++s) {
            __syncthreads();                     // bbuf reads of prev stage done
            const ushort* src = kqb + s * 16384;
#pragma unroll
            for (int i = 0; i < 8; ++i) {
                int q = wid * 8 + i;
                gld16(src + q * 512 + ln * 8, bbuf + q * 1024);
            }
            __syncthreads();                     // vmcnt drained: chunk ready
            __builtin_amdgcn_s_setprio(1);
#pragma unroll
            for (int ksl = 0; ksl < 2; ++ksl) {
                int kb = (((s >> 1) * 2 + ksl) * 64 + lg * 16) ^ ((lr & 7) << 4);
                bf16x8 a0 = *(const bf16x8*)(arena + lr * 512 + kb);
                bf16x8 a1 = *(const bf16x8*)(arena + (16 + lr) * 512 + kb);
#pragma unroll
                for (int nb = 0; nb < 4; ++nb) {
                    int nl = wid * 64 + nb * 16 + lr;
                    int slot = (ksl * 4 + lg) ^ (nl & 7);
                    bf16x8 bf = *(const bf16x8*)(bbuf + nl * 128 + slot * 16);
                    int g = (s & 1) * 4 + nb;
                    sac[0][g] = __builtin_amdgcn_mfma_f32_16x16x32_bf16(a0, bf, sac[0][g], 0, 0, 0);
                    sac[1][g] = __builtin_amdgcn_mfma_f32_16x16x32_bf16(a1, bf, sac[1][g], 0, 0, 0);
                }
            }
            __builtin_amdgcn_s_setprio(0);
        }
        // ---- softmax (rows m; n spread over g and lr)
        float pmax[2][4];
#pragma unroll
        for (int mb = 0; mb < 2; ++mb)
#pragma unroll
            for (int r = 0; r < 4; ++r) {
                float m = sac[mb][0][r];
#pragma unroll
                for (int g = 1; g < 8; ++g) m = fmaxf(m, sac[mb][g][r]);
#pragma unroll
                for (int o = 8; o >= 1; o >>= 1) m = fmaxf(m, __shfl_xor(m, o));
                pmax[mb][r] = m;
            }
        if (lr == 0) {
#pragma unroll
            for (int mb = 0; mb < 2; ++mb)
#pragma unroll
                for (int r = 0; r < 4; ++r)
                    smax[(mb * 16 + lg * 4 + r) * 4 + wid] = pmax[mb][r];
        }
        __syncthreads();    // also: all Xs reads complete before P overwrites
        float psum[2][4];
#pragma unroll
        for (int mb = 0; mb < 2; ++mb)
#pragma unroll
            for (int r = 0; r < 4; ++r) {
                int m = mb * 16 + lg * 4 + r;
                float g2 = fmaxf(fmaxf(smax[m * 4], smax[m * 4 + 1]),
                                 fmaxf(smax[m * 4 + 2], smax[m * 4 + 3]));
                float s = 0.f;
#pragma unroll
                for (int g = 0; g < 8; ++g) {
                    float e = __expf(sac[mb][g][r] - g2);
                    s += e;
                    int n = (g >> 2) * 256 + wid * 64 + (g & 3) * 16 + lr;
                    *(ushort*)(arena + m * 1024 + ((2 * n) ^ ((m & 7) << 4))) = f2bf(e);
                }
#pragma unroll
                for (int o = 8; o >= 1; o >>= 1) s += __shfl_xor(s, o);
                psum[mb][r] = s;
            }
        if (lr == 0) {
#pragma unroll
            for (int mb = 0; mb < 2; ++mb)
#pragma unroll
                for (int r = 0; r < 4; ++r)
                    ssum[(mb * 16 + lg * 4 + r) * 4 + wid] = psum[mb][r];
        }
        __syncthreads();
#pragma unroll
        for (int mb = 0; mb < 2; ++mb)
#pragma unroll
            for (int r = 0; r < 4; ++r) {
                int m = mb * 16 + lg * 4 + r;
                rinv[mb][r] = 1.0f / (ssum[m * 4] + ssum[m * 4 + 1] + ssum[m * 4 + 2] + ssum[m * 4 + 3]);
            }
    }

    // ---- Phase 3: out = (P @ vo) * rinv + bo, staged B.
    {
        f32x4 oac[2][4];
#pragma unroll
        for (int mb = 0; mb < 2; ++mb)
#pragma unroll
            for (int nb = 0; nb < 4; ++nb) oac[mb][nb] = (f32x4){0.f, 0.f, 0.f, 0.f};
        const ushort* vob = voc + (size_t)b * 131072;
        for (int s2 = 0; s2 < 8; ++s2) {
            __syncthreads();                     // bbuf reads of prev stage done
            const ushort* src = vob + s2 * 16384;
#pragma unroll
            for (int i = 0; i < 8; ++i) {
                int q = wid * 8 + i;
                gld16(src + q * 512 + ln * 8, bbuf + q * 1024);
            }
            __syncthreads();                     // chunk ready
            __builtin_amdgcn_s_setprio(1);
#pragma unroll
            for (int ksl = 0; ksl < 2; ++ksl) {
                int kb = ((s2 * 2 + ksl) * 64 + lg * 16) ^ ((lr & 7) << 4);
                bf16x8 a0 = *(const bf16x8*)(arena + lr * 1024 + kb);
                bf16x8 a1 = *(const bf16x8*)(arena + (16 + lr) * 1024 + kb);
#pragma unroll
                for (int nb = 0; nb < 4; ++nb) {
                    int d = wid * 64 + nb * 16 + lr;
                    int slot = (ksl * 4 + lg) ^ (d & 7);
                    bf16x8 bf = *(const bf16x8*)(bbuf + d * 128 + slot * 16);
                    oac[0][nb] = __builtin_amdgcn_mfma_f32_16x16x32_bf16(a0, bf, oac[0][nb], 0, 0, 0);
                    oac[1][nb] = __builtin_amdgcn_mfma_f32_16x16x32_bf16(a1, bf, oac[1][nb], 0, 0, 0);
                }
            }
            __builtin_amdgcn_s_setprio(0);
        }
        size_t afbase = ((size_t)b * C + ci) * H * W;
#pragma unroll
        for (int nb = 0; nb < 4; ++nb) {
            int h = wid * 64 + nb * 16 + lr;
            float bias = bo[h];
            ushort* op = af16 + afbase + (size_t)h * W + w0;
#pragma unroll
            for (int mb = 0; mb < 2; ++mb) {
                ushort4 u;
                u.x = f2bf(oac[mb][nb][0] * rinv[mb][0] + bias);
                u.y = f2bf(oac[mb][nb][1] * rinv[mb][1] + bias);
                u.z = f2bf(oac[mb][nb][2] * rinv[mb][2] + bias);
                u.w = f2bf(oac[mb][nb][3] * rinv[mb][3] + bias);
                *(ushort4*)(op + mb * 16 + lg * 4) = u;
            }
        }
    }
}

// ---------------------------------------------------------------------------
// Build conv-ready catn: [b][y][ix=0..513][256cc] bf16, x-halo baked,
// 16-B units pre-swizzled (round-8 proven). + XCD swizzle.
__launch_bounds__(256)
__global__ void k_cat(const float* __restrict__ x, const ushort* __restrict__ af16,
                      const float* __restrict__ bin, ushort* __restrict__ catn) {
    __shared__ __align__(16) char st[32768];
    const int t   = threadIdx.x;
    const int blk = xcdswz(blockIdx.x, 512);     // 4096 blocks
    const int xt  = blk & 7;
    const int y   = (blk >> 3) & 255;
    const int b   = blk >> 11;
    const int x0  = xt * 64;
    const float bw = bin[y];

    for (int i = t; i < 2048; i += 256) {
        int cc = i >> 4, c4 = i & 15;
        float4 v = *(const float4*)(x + (((size_t)b * C + cc) * H + y) * W + x0 + c4 * 4);
#pragma unroll
        for (int j = 0; j < 4; ++j) {
            int px = c4 * 4 + j;
            float f = (j == 0 ? v.x : j == 1 ? v.y : j == 2 ? v.z : v.w) * bw;
            *(ushort*)(st + px * 512 + ((2 * cc) ^ ((px & 7) << 4))) = f2bf(f);
        }
    }
    for (int i = t; i < 1024; i += 256) {
        int cc = i >> 3, c8 = i & 7;
        U8 v;
        v.v = *(const bf16x8*)(af16 + (((size_t)b * C + cc) * H + y) * W + x0 + c8 * 8);
#pragma unroll
        for (int j = 0; j < 8; ++j) {
            int px = c8 * 8 + j;
            *(ushort*)(st + px * 512 + ((2 * (128 + cc)) ^ ((px & 7) << 4))) = v.u[j];
        }
    }
    __syncthreads();
    const size_t rowb = ((size_t)b * H + y) * 514;
    for (int i = t; i < 2048; i += 256) {
        int px = i >> 5, c16 = i & 31;          // output slot (px, c16)
        int c = c16 >> 3, cgs = c16 & 7;
        int ix = x0 + px + 1;                   // catn x-index for gx = x0+px
        int cgl = cgs ^ (ix & 7);               // logical unit stored at this slot
        bf16x8 v = *(const bf16x8*)(st + px * 512 + ((((c << 3) | cgl) << 4) ^ ((px & 7) << 4)));
        *(bf16x8*)(catn + (rowb + ix) * 256 + c * 64 + cgs * 8) = v;
    }
    const bf16x8 z = {0, 0, 0, 0, 0, 0, 0, 0};
    if (xt == 0 && t < 32) *(bf16x8*)(catn + (rowb + 0) * 256 + t * 8) = z;
    if (xt == 7 && t < 32) *(bf16x8*)(catn + (rowb + 513) * 256 + t * 8) = z;
}

// ---------------------------------------------------------------------------
// MFMA conv3x3, GEMM-shaped (round-9 proven: gload_lds input + LDS weights,
// inline weight ds_reads interleaved with MFMAs by the compiler). + XCD swizzle.
__launch_bounds__(512, 4)
__global__ void k_convg(const ushort* __restrict__ catn, const ushort* __restrict__ w9p,
                        const float* __restrict__ conv_b, float* __restrict__ out,
                        float* __restrict__ pb) {
    __shared__ __align__(16) char stf[55296];    // input: 6 rows * 72 px * 128 B
    __shared__ __align__(16) char wls[16384];    // weights: 128 co * 128 B
    __shared__ float pst[4][64];
    const int t   = threadIdx.x;
    const int ln  = t & 63;
    const int blk = xcdswz(blockIdx.x, 128);     // 1024 blocks
    const int xt  = blk & 7;
    const int yq  = (blk >> 3) & 63;
    const int b   = blk >> 9;
    const int x0  = xt * 64;
    const int y0  = yq * 4;
    const int wid = t >> 6;
    const int wm  = wid >> 1;        // output row within quad (0..3)
    const int wn  = wid & 1;         // co half (0..1)
    const int lr  = t & 15;
    const int lg  = (t & 63) >> 4;
    const ushort* cbase = catn + (size_t)b * ((size_t)H * 514 * 256);

    f32x4 acc[4][4];
#pragma unroll
    for (int mb = 0; mb < 4; ++mb)
#pragma unroll
        for (int nb = 0; nb < 4; ++nb) acc[mb][nb] = (f32x4){0.f, 0.f, 0.f, 0.f};

    for (int c = 0; c < 4; ++c) {                // 64-cc chunk
        __syncthreads();                         // prev chunk's LDS reads done
        for (int q = wid; q < 54; q += 8) {
            int r = q / 9, seg = q - r * 9;
            int iy = y0 - 1 + r;
            char* ldsb = stf + r * 9216 + seg * 1024;
            if ((unsigned)iy < (unsigned)H) {    // wave-uniform branch
                const ushort* src = cbase + ((size_t)iy * 514 + x0 + seg * 8 + (ln >> 3)) * 256
                                  + c * 64 + (ln & 7) * 8;
                gld16(src, ldsb);
            } else {
                *(f32x4*)(ldsb + ln * 16) = (f32x4){0.f, 0.f, 0.f, 0.f};
            }
        }
        {
            const ushort* wsrc = w9p + (size_t)(c * 9 + 0) * 8192;
#pragma unroll
            for (int q = wid * 2; q < wid * 2 + 2; ++q)
                gld16(wsrc + q * 512 + ln * 8, wls + q * 1024);
        }
        __syncthreads();                         // drains vmcnt: input + w[0] ready

        for (int p = 0; p < 9; ++p) {
            const int dy = p / 3, dx = p - dy * 3;
            const char* arow = stf + (wm + dy) * 9216;
#pragma unroll
            for (int ks = 0; ks < 2; ++ks) {
                bf16x8 afr[4];
#pragma unroll
                for (int mb = 0; mb < 4; ++mb) {
                    int px = mb * 16 + lr + dx;
                    afr[mb] = *(const bf16x8*)(arow + px * 128 + ((ks * 64 + lg * 16) ^ ((px & 7) << 4)));
                }
                bf16x8 bfr[4];
#pragma unroll
                for (int nb = 0; nb < 4; ++nb) {
                    int co = wn * 64 + nb * 16 + lr;
                    bfr[nb] = *(const bf16x8*)(wls + co * 128 + ((ks * 64 + lg * 16) ^ ((co & 7) << 4)));
                }
#pragma unroll
                for (int nb = 0; nb < 4; ++nb)
#pragma unroll
                    for (int mb = 0; mb < 4; ++mb)
                        acc[mb][nb] = __builtin_amdgcn_mfma_f32_16x16x32_bf16(afr[mb], bfr[nb], acc[mb][nb], 0, 0, 0);
            }
            if (p < 8) {
                __syncthreads();                 // all waves done reading wls
                const ushort* wsrc = w9p + (size_t)(c * 9 + p + 1) * 8192;
#pragma unroll
                for (int q = wid * 2; q < wid * 2 + 2; ++q)
                    gld16(wsrc + q * 512 + ln * 8, wls + q * 1024);
                __syncthreads();                 // w[p+1] ready
            }
        }
    }

#pragma unroll
    for (int nb = 0; nb < 4; ++nb) {
        int co = wn * 64 + nb * 16 + lr;
        float bias = conv_b[co];
        float s = 0.f, ss = 0.f;
        float* op = out + (((size_t)b * C + co) * H + (y0 + wm)) * W + x0;
#pragma unroll
        for (int mb = 0; mb < 4; ++mb) {
            float4 o = make_float4(acc[mb][nb][0] + bias, acc[mb][nb][1] + bias,
                                   acc[mb][nb][2] + bias, acc[mb][nb][3] + bias);
            s  += (o.x + o.y) + (o.z + o.w);
            ss += (o.x * o.x + o.y * o.y) + (o.z * o.z + o.w * o.w);
            *(float4*)(op + mb * 16 + lg * 4) = o;
        }
        s += __shfl_xor(s, 1);  ss += __shfl_xor(ss, 1);    // co within group of 4
        s += __shfl_xor(s, 2);  ss += __shfl_xor(ss, 2);
        s += __shfl_xor(s, 16); ss += __shfl_xor(ss, 16);   // px quarters (lg)
        s += __shfl_xor(s, 32); ss += __shfl_xor(ss, 32);
        if (lg == 0 && (lr & 3) == 0) {
            int g = co >> 2;
            pst[wm][g * 2]     = s;
            pst[wm][g * 2 + 1] = ss;
        }
    }
    __syncthreads();
    if (t < 64)
        pb[(size_t)blk * 64 + t] = pst[0][t] + pst[1][t] + pst[2][t] + pst[3][t];
}

// ---------------------------------------------------------------------------
__global__ void k_stats2(const float* __restrict__ pb, float* __restrict__ st2) {
    __shared__ float red[512];
    int blk = blockIdx.x;            // b*32 + g
    int b = blk >> 5, g = blk & 31;
    int t = threadIdx.x;
    float s = 0.f, ss = 0.f;
    for (int j = t; j < 512; j += 256) {
        const float* p = pb + ((size_t)(b * 512 + j)) * 64 + g * 2;
        s += p[0]; ss += p[1];
    }
    red[t * 2] = s; red[t * 2 + 1] = ss;
    __syncthreads();
    for (int o = 128; o >= 1; o >>= 1) {
        if (t < o) {
            red[t * 2]     += red[(t + o) * 2];
            red[t * 2 + 1] += red[(t + o) * 2 + 1];
        }
        __syncthreads();
    }
    if (t == 0) {
        const float inv = 1.0f / 524288.0f;
        float mean = red[0] * inv;
        float var  = red[1] * inv - mean * mean;
        st2[blk * 2]     = mean;
        st2[blk * 2 + 1] = rsqrtf(var + 1e-6f);
    }
}

__global__ void k_norm(const float* __restrict__ st2, const float* __restrict__ gamma,
                       const float* __restrict__ beta, float* __restrict__ out) {
    const int N4 = B * C * H * W / 4;
    int stride = gridDim.x * 256;
    for (int i4 = blockIdx.x * 256 + threadIdx.x; i4 < N4; i4 += stride) {
        int i = i4 * 4;
        int c = (i >> 17) & 127;
        int b = i >> 24;
        int g = c >> 2;
        float mean = st2[(b * 32 + g) * 2];
        float rstd = st2[(b * 32 + g) * 2 + 1];
        float ga = gamma[c], be = beta[c];
        float4 v = *(float4*)(out + i);
        float n0 = (v.x - mean) * rstd * ga + be;
        float n1 = (v.y - mean) * rstd * ga + be;
        float n2 = (v.z - mean) * rstd * ga + be;
        float n3 = (v.w - mean) * rstd * ga + be;
        v.x = n0 / (1.0f + __expf(-n0));
        v.y = n1 / (1.0f + __expf(-n1));
        v.z = n2 / (1.0f + __expf(-n2));
        v.w = n3 / (1.0f + __expf(-n3));
        *(float4*)(out + i) = v;
    }
}

// ---------------------------------------------------------------------------
extern "C" void kernel_launch(void* const* d_in, const int* in_sizes, int n_in,
                              void* d_out, int out_size, void* d_ws, size_t ws_size,
                              hipStream_t stream) {
    const float* x      = (const float*)d_in[0];
    const float* v      = (const float*)d_in[1];
    const float* Wq     = (const float*)d_in[2];
    const float* Wk     = (const float*)d_in[3];
    const float* Wv     = (const float*)d_in[4];
    const float* Wo     = (const float*)d_in[5];
    const float* bo     = (const float*)d_in[6];
    const float* mask_w = (const float*)d_in[7];
    const float* conv_w = (const float*)d_in[8];
    const float* conv_b = (const float*)d_in[9];
    const float* gng    = (const float*)d_in[10];
    const float* gnb    = (const float*)d_in[11];

    float* out  = (float*)d_out;
    float* mout = out + B * C * H * W;
    // d_out's out-region is dead until k_convg writes it -> first 64 MB holds
    // the bf16 attn feature (consumed by k_cat strictly before k_convg).
    ushort* af16 = (ushort*)d_out;

    char*  wsb  = (char*)d_ws;
    ushort* catn  = (ushort*)(wsb + WS_CATN);
    ushort* kqc   = (ushort*)(wsb + WS_KQ);
    ushort* voc   = (ushort*)(wsb + WS_VOT);
    ushort* w9p   = (ushort*)(wsb + WS_W9);
    float*  bin   = (float*)(wsb + WS_BIN);
    float*  st2   = (float*)(wsb + WS_ST2);
    // pb (1024 blocks x 64 f32 = 256 KB) aliases kqc region (dead after k_attn).
    float*  pb    = (float*)(wsb + WS_KQ);

    k_binary <<<1,    256, 0, stream>>>(mask_w, bin);
    k_maskout<<<1024, 256, 0, stream>>>(bin, mout);
    k_kv     <<<B * NCOND, 256, 0, stream>>>(v, Wk, Wv, Wq, Wo, kqc, voc);
    k_w9p    <<<1152, 256, 0, stream>>>(conv_w, w9p);
    k_attn   <<<4096, 256, 0, stream>>>(x, kqc, voc, bo, af16);
    k_cat    <<<4096, 256, 0, stream>>>(x, af16, bin, catn);
    k_convg  <<<1024, 512, 0, stream>>>(catn, w9p, conv_b, out, pb);
    k_stats2 <<<64,   256, 0, stream>>>(pb, st2);
    k_norm   <<<2048, 256, 0, stream>>>(st2, gng, gnb, out);
}

// Round 14
// 506.389 us; speedup vs baseline: 1.1842x; 1.1842x over previous
//
#include <hip/hip_runtime.h>
#include <math.h>

// Problem constants (from reference setup_inputs)
#define B      2
#define C      128     // channels
#define H      256     // d_model == image height
#define W      512     // image width
#define NCOND  512
#define DCOND  512
#define DATTN  256
#define KKEEP  204     // int(256 * (1 - 0.2))

// Workspace layout (byte offsets). Total ~136.4 MB.
// catn: bf16, x-halo baked rows of 514 px, 256 cc, XOR-preswizzled 16B units.
// kqc:  bf16 S-phase B, chunked [b][s=ks2*2+nh][256 n][64 h], slot u^(n&7)
// voc:  bf16 PV-phase B, chunked [b][s2][256 d][64 n], slot u^(d&7)
#define WS_CATN   0ull          // [B][256][514][256] bf16 = 134742016 B
#define WS_KQ     134742016ull  // kqc  [2][8][256][64]     524288 B (pb aliases after attn)
#define WS_VOT    135266304ull  // voc  [2][8][256][64]     524288 B
#define WS_W9     135790592ull  // bf16 w9p [36][128co][64] 589824 B (16KB per (c,p), preswizzled)
#define WS_BIN    136380416ull  // f32 binary[256]          1024 B
#define WS_ST2    136381440ull  // f32 stats [B][32][2]     512 B

typedef __attribute__((ext_vector_type(8))) short bf16x8;
typedef __attribute__((ext_vector_type(4))) float f32x4;

union U8 { bf16x8 v; ushort u[8]; };

__device__ inline ushort f2bf(float f) {
    union { float f; unsigned u; } v; v.f = f;
    unsigned r = v.u + 0x7fffu + ((v.u >> 16) & 1u);   // RNE
    return (ushort)(r >> 16);
}

// Direct global->LDS async copy, 16 B/lane (dest = uniform base + lane*16).
__device__ __forceinline__ void gld16(const ushort* g, void* l) {
    __builtin_amdgcn_global_load_lds(
        (const __attribute__((address_space(1))) unsigned int*)(const void*)g,
        (__attribute__((address_space(3))) unsigned int*)l, 16, 0, 0);
}

// ---------------------------------------------------------------------------
// Learned mask: binary[h] = 1 iff sigmoid(mask_w[h]) is among the top-204.
__global__ void k_binary(const float* __restrict__ mask_w, float* __restrict__ bin) {
    __shared__ float s[H];
    int t = threadIdx.x;
    float sv = 1.0f / (1.0f + __expf(-mask_w[t]));
    s[t] = sv;
    __syncthreads();
    int cnt = 0;
    for (int j = 0; j < H; ++j) cnt += (s[j] > sv) ? 1 : 0;
    bin[t] = (cnt < KKEEP) ? 1.0f : 0.0f;
}

__global__ void k_maskout(const float* __restrict__ bin, float* __restrict__ mout) {
    int i = blockIdx.x * 256 + threadIdx.x;
    if (i < B * W * H) mout[i] = bin[i & (H - 1)];
}

// ---------------------------------------------------------------------------
// K/V projection + weight folding (associativity):
//   kq[b][n][h]  = sum_d (v.Wk)[n,d] * Wq[h,d]   (S = X @ kq^T)
//   vo[b][n][h]  = sum_d (v.Wv)[n,d] * Wo[d,h]   (out = P @ vo)
// Outputs written in the stage-chunked, pre-swizzled layouts k_attn stages.
__launch_bounds__(256)
__global__ void k_kv(const float* __restrict__ v, const float* __restrict__ Wk,
                     const float* __restrict__ Wv, const float* __restrict__ Wq,
                     const float* __restrict__ Wo, ushort* __restrict__ kqc,
                     ushort* __restrict__ voc) {
    __shared__ float vrow[DCOND];
    __shared__ float kld[DATTN];
    __shared__ float vld[DATTN];
    int bn = blockIdx.x;              // b*NCOND + n
    int t  = threadIdx.x;
    const float* vp = v + (size_t)bn * DCOND;
    for (int i = t; i < DCOND; i += 256) vrow[i] = vp[i];
    __syncthreads();
    float ka = 0.f, va = 0.f;
    for (int d4 = 0; d4 < DCOND / 4; ++d4) {
        float4 vv = *(const float4*)(vrow + d4 * 4);
        const float* wk = Wk + (d4 * 4) * DATTN + t;
        const float* wv = Wv + (d4 * 4) * DATTN + t;
        ka += vv.x * wk[0];         va += vv.x * wv[0];
        ka += vv.y * wk[DATTN];     va += vv.y * wv[DATTN];
        ka += vv.z * wk[2 * DATTN]; va += vv.z * wv[2 * DATTN];
        ka += vv.w * wk[3 * DATTN]; va += vv.w * wv[3 * DATTN];
    }
    kld[t] = ka; vld[t] = va;
    __syncthreads();
    float kq = 0.f;
    const float4* wqr = (const float4*)(Wq + (size_t)t * DATTN);
#pragma unroll 8
    for (int d4 = 0; d4 < DATTN / 4; ++d4) {
        float4 w = wqr[d4];
        kq += kld[d4 * 4] * w.x + kld[d4 * 4 + 1] * w.y
            + kld[d4 * 4 + 2] * w.z + kld[d4 * 4 + 3] * w.w;
    }
    float vo = 0.f;
#pragma unroll 8
    for (int d = 0; d < DATTN; ++d) vo += vld[d] * Wo[(size_t)d * 256 + t];

    int b = bn >> 9, n = bn & 511;
    // kqc: chunk s = (h>>6)*2 + (n>>8); row n&255 (128 B); unit u=(h>>3)&7 at slot u^(n&7)
    {
        int s    = ((t >> 6) << 1) | (n >> 8);
        int nl   = n & 255;
        int slot = (((t >> 3) & 7) ^ (n & 7));
        kqc[(((size_t)(b * 8 + s)) * 256 + nl) * 64 + slot * 8 + (t & 7)] = f2bf(kq);
    }
    // voc: chunk s2 = n>>6; row d=t (128 B); unit u=(n>>3)&7 at slot u^(d&7)
    {
        int s2   = n >> 6;
        int slot = (((n >> 3) & 7) ^ (t & 7));
        voc[(((size_t)(b * 8 + s2)) * 256 + t) * 64 + slot * 8 + (n & 7)] = f2bf(vo);
    }
}

// conv weights -> w9p[(c*9+p)][co][64 ush], pre-swizzled for LDS image:
// 16B unit slot us of row co holds logical unit us ^ (co&7).
__global__ void k_w9p(const float* __restrict__ cw, ushort* __restrict__ w9p) {
    int i = blockIdx.x * 256 + threadIdx.x;
    if (i >= 294912) return;          // 36 * 128 * 64
    int cp = i >> 13;                 // c*9 + p
    int r  = i & 8191;
    int co = r >> 6;
    int u  = r & 63;
    int us = u >> 3, j = u & 7;
    int c  = cp / 9, p = cp - c * 9;
    int cc = ((us ^ (co & 7)) << 3) | j;          // logical cc within chunk
    int ci = c * 64 + cc;
    w9p[(size_t)cp * 8192 + co * 64 + u] = f2bf(cw[(co * 256 + ci) * 9 + p]);
}

// ---------------------------------------------------------------------------
// Fused MFMA cross-attention, 2-GEMM form with async-staged B operands.
// Block = 32 rows (b, ci, w0..w0+31), 4 waves.  LDS: arena 33.8 KB (X then P)
// + bbuf 32 KB (staged B chunk) = 66.5 KB -> 2 blocks/CU (stage/compute of the
// two blocks interleave).  All B reads are conflict-free swizzled ds_read_b128.
__launch_bounds__(256)
__global__ void k_attn(const float* __restrict__ x, const ushort* __restrict__ kqc,
                       const ushort* __restrict__ voc, const float* __restrict__ bo,
                       ushort* __restrict__ af16) {
    __shared__ __align__(16) char arena[33792];
    __shared__ __align__(16) char bbuf[32768];
    float* smax = (float*)(arena + 32768);
    float* ssum = (float*)(arena + 33280);

    const int t   = threadIdx.x;
    const int ln  = t & 63;
    const int blk = blockIdx.x;
    const int b   = blk >> 11;
    const int ci  = (blk >> 4) & 127;
    const int w0  = (blk & 15) << 5;
    const int wid = t >> 6;
    const int lr  = t & 15;
    const int lg  = (t & 63) >> 4;

    // ---- Phase 1: load X tile -> Xs[w][h] bf16 (thread t = h)
    {
        const float* xp = x + (((size_t)b * C + ci) * H + t) * W + w0;
#pragma unroll
        for (int j4 = 0; j4 < 8; ++j4) {
            float4 v4 = *(const float4*)(xp + j4 * 4);
            int j = j4 * 4;
            *(ushort*)(arena + (j + 0) * 512 + ((2 * t) ^ (((j + 0) & 7) << 4))) = f2bf(v4.x);
            *(ushort*)(arena + (j + 1) * 512 + ((2 * t) ^ (((j + 1) & 7) << 4))) = f2bf(v4.y);
            *(ushort*)(arena + (j + 2) * 512 + ((2 * t) ^ (((j + 2) & 7) << 4))) = f2bf(v4.z);
            *(ushort*)(arena + (j + 3) * 512 + ((2 * t) ^ (((j + 3) & 7) << 4))) = f2bf(v4.w);
        }
    }

    // ---- Phase 2: S = Xs @ kq^T, staged B.  Stage s covers h = (s>>1)*64..+63,
    // n-half (s&1)*256.  Wave's n within stage: wid*64 + nb*16 + lr.
    float rinv[2][4];
    {
        f32x4 sac[2][8];
#pragma unroll
        for (int mb = 0; mb < 2; ++mb)
#pragma unroll
            for (int g = 0; g < 8; ++g) sac[mb][g] = (f32x4){0.f, 0.f, 0.f, 0.f};
        const ushort* kqb = kqc + (size_t)b * 131072;
        for (int s = 0; s < 8; ++s) {
            __syncthreads();                     // bbuf reads of prev stage done
            const ushort* src = kqb + s * 16384;
#pragma unroll
            for (int i = 0; i < 8; ++i) {
                int q = wid * 8 + i;
                gld16(src + q * 512 + ln * 8, bbuf + q * 1024);
            }
            __syncthreads();                     // vmcnt drained: chunk ready
#pragma unroll
            for (int ksl = 0; ksl < 2; ++ksl) {
                int kb = (((s >> 1) * 2 + ksl) * 64 + lg * 16) ^ ((lr & 7) << 4);
                bf16x8 a0 = *(const bf16x8*)(arena + lr * 512 + kb);
                bf16x8 a1 = *(const bf16x8*)(arena + (16 + lr) * 512 + kb);
#pragma unroll
                for (int nb = 0; nb < 4; ++nb) {
                    int nl = wid * 64 + nb * 16 + lr;
                    int slot = (ksl * 4 + lg) ^ (nl & 7);
                    bf16x8 bf = *(const bf16x8*)(bbuf + nl * 128 + slot * 16);
                    int g = (s & 1) * 4 + nb;
                    sac[0][g] = __builtin_amdgcn_mfma_f32_16x16x32_bf16(a0, bf, sac[0][g], 0, 0, 0);
                    sac[1][g] = __builtin_amdgcn_mfma_f32_16x16x32_bf16(a1, bf, sac[1][g], 0, 0, 0);
                }
            }
        }
        // ---- softmax (rows m; n spread over g and lr)
        float pmax[2][4];
#pragma unroll
        for (int mb = 0; mb < 2; ++mb)
#pragma unroll
            for (int r = 0; r < 4; ++r) {
                float m = sac[mb][0][r];
#pragma unroll
                for (int g = 1; g < 8; ++g) m = fmaxf(m, sac[mb][g][r]);
#pragma unroll
                for (int o = 8; o >= 1; o >>= 1) m = fmaxf(m, __shfl_xor(m, o));
                pmax[mb][r] = m;
            }
        if (lr == 0) {
#pragma unroll
            for (int mb = 0; mb < 2; ++mb)
#pragma unroll
                for (int r = 0; r < 4; ++r)
                    smax[(mb * 16 + lg * 4 + r) * 4 + wid] = pmax[mb][r];
        }
        __syncthreads();    // also: all Xs reads complete before P overwrites
        float psum[2][4];
#pragma unroll
        for (int mb = 0; mb < 2; ++mb)
#pragma unroll
            for (int r = 0; r < 4; ++r) {
                int m = mb * 16 + lg * 4 + r;
                float g2 = fmaxf(fmaxf(smax[m * 4], smax[m * 4 + 1]),
                                 fmaxf(smax[m * 4 + 2], smax[m * 4 + 3]));
                float s = 0.f;
#pragma unroll
                for (int g = 0; g < 8; ++g) {
                    float e = __expf(sac[mb][g][r] - g2);
                    s += e;
                    int n = (g >> 2) * 256 + wid * 64 + (g & 3) * 16 + lr;
                    *(ushort*)(arena + m * 1024 + ((2 * n) ^ ((m & 7) << 4))) = f2bf(e);
                }
#pragma unroll
                for (int o = 8; o >= 1; o >>= 1) s += __shfl_xor(s, o);
                psum[mb][r] = s;
            }
        if (lr == 0) {
#pragma unroll
            for (int mb = 0; mb < 2; ++mb)
#pragma unroll
                for (int r = 0; r < 4; ++r)
                    ssum[(mb * 16 + lg * 4 + r) * 4 + wid] = psum[mb][r];
        }
        __syncthreads();
#pragma unroll
        for (int mb = 0; mb < 2; ++mb)
#pragma unroll
            for (int r = 0; r < 4; ++r) {
                int m = mb * 16 + lg * 4 + r;
                rinv[mb][r] = 1.0f / (ssum[m * 4] + ssum[m * 4 + 1] + ssum[m * 4 + 2] + ssum[m * 4 + 3]);
            }
    }

    // ---- Phase 3: out = (P @ vo) * rinv + bo, staged B.  Stage s2 covers
    // n = s2*64..+63 for all 256 d.
    {
        f32x4 oac[2][4];
#pragma unroll
        for (int mb = 0; mb < 2; ++mb)
#pragma unroll
            for (int nb = 0; nb < 4; ++nb) oac[mb][nb] = (f32x4){0.f, 0.f, 0.f, 0.f};
        const ushort* vob = voc + (size_t)b * 131072;
        for (int s2 = 0; s2 < 8; ++s2) {
            __syncthreads();                     // bbuf reads of prev stage done
            const ushort* src = vob + s2 * 16384;
#pragma unroll
            for (int i = 0; i < 8; ++i) {
                int q = wid * 8 + i;
                gld16(src + q * 512 + ln * 8, bbuf + q * 1024);
            }
            __syncthreads();                     // chunk ready
#pragma unroll
            for (int ksl = 0; ksl < 2; ++ksl) {
                int kb = ((s2 * 2 + ksl) * 64 + lg * 16) ^ ((lr & 7) << 4);
                bf16x8 a0 = *(const bf16x8*)(arena + lr * 1024 + kb);
                bf16x8 a1 = *(const bf16x8*)(arena + (16 + lr) * 1024 + kb);
#pragma unroll
                for (int nb = 0; nb < 4; ++nb) {
                    int d = wid * 64 + nb * 16 + lr;
                    int slot = (ksl * 4 + lg) ^ (d & 7);
                    bf16x8 bf = *(const bf16x8*)(bbuf + d * 128 + slot * 16);
                    oac[0][nb] = __builtin_amdgcn_mfma_f32_16x16x32_bf16(a0, bf, oac[0][nb], 0, 0, 0);
                    oac[1][nb] = __builtin_amdgcn_mfma_f32_16x16x32_bf16(a1, bf, oac[1][nb], 0, 0, 0);
                }
            }
        }
        size_t afbase = ((size_t)b * C + ci) * H * W;
#pragma unroll
        for (int nb = 0; nb < 4; ++nb) {
            int h = wid * 64 + nb * 16 + lr;
            float bias = bo[h];
            ushort* op = af16 + afbase + (size_t)h * W + w0;
#pragma unroll
            for (int mb = 0; mb < 2; ++mb) {
                ushort4 u;
                u.x = f2bf(oac[mb][nb][0] * rinv[mb][0] + bias);
                u.y = f2bf(oac[mb][nb][1] * rinv[mb][1] + bias);
                u.z = f2bf(oac[mb][nb][2] * rinv[mb][2] + bias);
                u.w = f2bf(oac[mb][nb][3] * rinv[mb][3] + bias);
                *(ushort4*)(op + mb * 16 + lg * 4) = u;
            }
        }
    }
}

// ---------------------------------------------------------------------------
// Build conv-ready catn: [b][y][ix=0..513][256cc] bf16, x-halo baked,
// 16-B units pre-swizzled (round-8 proven).
__launch_bounds__(256)
__global__ void k_cat(const float* __restrict__ x, const ushort* __restrict__ af16,
                      const float* __restrict__ bin, ushort* __restrict__ catn) {
    __shared__ __align__(16) char st[32768];
    const int t   = threadIdx.x;
    const int blk = blockIdx.x;
    const int xt  = blk & 7;
    const int y   = (blk >> 3) & 255;
    const int b   = blk >> 11;
    const int x0  = xt * 64;
    const float bw = bin[y];

    for (int i = t; i < 2048; i += 256) {
        int cc = i >> 4, c4 = i & 15;
        float4 v = *(const float4*)(x + (((size_t)b * C + cc) * H + y) * W + x0 + c4 * 4);
#pragma unroll
        for (int j = 0; j < 4; ++j) {
            int px = c4 * 4 + j;
            float f = (j == 0 ? v.x : j == 1 ? v.y : j == 2 ? v.z : v.w) * bw;
            *(ushort*)(st + px * 512 + ((2 * cc) ^ ((px & 7) << 4))) = f2bf(f);
        }
    }
    for (int i = t; i < 1024; i += 256) {
        int cc = i >> 3, c8 = i & 7;
        U8 v;
        v.v = *(const bf16x8*)(af16 + (((size_t)b * C + cc) * H + y) * W + x0 + c8 * 8);
#pragma unroll
        for (int j = 0; j < 8; ++j) {
            int px = c8 * 8 + j;
            *(ushort*)(st + px * 512 + ((2 * (128 + cc)) ^ ((px & 7) << 4))) = v.u[j];
        }
    }
    __syncthreads();
    const size_t rowb = ((size_t)b * H + y) * 514;
    for (int i = t; i < 2048; i += 256) {
        int px = i >> 5, c16 = i & 31;          // output slot (px, c16)
        int c = c16 >> 3, cgs = c16 & 7;
        int ix = x0 + px + 1;                   // catn x-index for gx = x0+px
        int cgl = cgs ^ (ix & 7);               // logical unit stored at this slot
        bf16x8 v = *(const bf16x8*)(st + px * 512 + ((((c << 3) | cgl) << 4) ^ ((px & 7) << 4)));
        *(bf16x8*)(catn + (rowb + ix) * 256 + c * 64 + cgs * 8) = v;
    }
    const bf16x8 z = {0, 0, 0, 0, 0, 0, 0, 0};
    if (xt == 0 && t < 32) *(bf16x8*)(catn + (rowb + 0) * 256 + t * 8) = z;
    if (xt == 7 && t < 32) *(bf16x8*)(catn + (rowb + 513) * 256 + t * 8) = z;
}

// ---------------------------------------------------------------------------
// MFMA conv3x3, GEMM-shaped (round-9 proven: gload_lds input + LDS weights).
__launch_bounds__(512, 4)
__global__ void k_convg(const ushort* __restrict__ catn, const ushort* __restrict__ w9p,
                        const float* __restrict__ conv_b, float* __restrict__ out,
                        float* __restrict__ pb) {
    __shared__ __align__(16) char stf[55296];    // input: 6 rows * 72 px * 128 B
    __shared__ __align__(16) char wls[16384];    // weights: 128 co * 128 B
    __shared__ float pst[4][64];
    const int t   = threadIdx.x;
    const int ln  = t & 63;
    const int blk = blockIdx.x;
    const int xt  = blk & 7;
    const int yq  = (blk >> 3) & 63;
    const int b   = blk >> 9;
    const int x0  = xt * 64;
    const int y0  = yq * 4;
    const int wid = t >> 6;
    const int wm  = wid >> 1;        // output row within quad (0..3)
    const int wn  = wid & 1;         // co half (0..1)
    const int lr  = t & 15;
    const int lg  = (t & 63) >> 4;
    const ushort* cbase = catn + (size_t)b * ((size_t)H * 514 * 256);

    f32x4 acc[4][4];
#pragma unroll
    for (int mb = 0; mb < 4; ++mb)
#pragma unroll
        for (int nb = 0; nb < 4; ++nb) acc[mb][nb] = (f32x4){0.f, 0.f, 0.f, 0.f};

    for (int c = 0; c < 4; ++c) {                // 64-cc chunk
        __syncthreads();                         // prev chunk's LDS reads done
        for (int q = wid; q < 54; q += 8) {
            int r = q / 9, seg = q - r * 9;
            int iy = y0 - 1 + r;
            char* ldsb = stf + r * 9216 + seg * 1024;
            if ((unsigned)iy < (unsigned)H) {    // wave-uniform branch
                const ushort* src = cbase + ((size_t)iy * 514 + x0 + seg * 8 + (ln >> 3)) * 256
                                  + c * 64 + (ln & 7) * 8;
                gld16(src, ldsb);
            } else {
                *(f32x4*)(ldsb + ln * 16) = (f32x4){0.f, 0.f, 0.f, 0.f};
            }
        }
        {
            const ushort* wsrc = w9p + (size_t)(c * 9 + 0) * 8192;
#pragma unroll
            for (int q = wid * 2; q < wid * 2 + 2; ++q)
                gld16(wsrc + q * 512 + ln * 8, wls + q * 1024);
        }
        __syncthreads();                         // drains vmcnt: input + w[0] ready

        for (int p = 0; p < 9; ++p) {
            const int dy = p / 3, dx = p - dy * 3;
            const char* arow = stf + (wm + dy) * 9216;
#pragma unroll
            for (int ks = 0; ks < 2; ++ks) {
                bf16x8 afr[4];
#pragma unroll
                for (int mb = 0; mb < 4; ++mb) {
                    int px = mb * 16 + lr + dx;
                    afr[mb] = *(const bf16x8*)(arow + px * 128 + ((ks * 64 + lg * 16) ^ ((px & 7) << 4)));
                }
                bf16x8 bfr[4];
#pragma unroll
                for (int nb = 0; nb < 4; ++nb) {
                    int co = wn * 64 + nb * 16 + lr;
                    bfr[nb] = *(const bf16x8*)(wls + co * 128 + ((ks * 64 + lg * 16) ^ ((co & 7) << 4)));
                }
#pragma unroll
                for (int nb = 0; nb < 4; ++nb)
#pragma unroll
                    for (int mb = 0; mb < 4; ++mb)
                        acc[mb][nb] = __builtin_amdgcn_mfma_f32_16x16x32_bf16(afr[mb], bfr[nb], acc[mb][nb], 0, 0, 0);
            }
            if (p < 8) {
                __syncthreads();                 // all waves done reading wls
                const ushort* wsrc = w9p + (size_t)(c * 9 + p + 1) * 8192;
#pragma unroll
                for (int q = wid * 2; q < wid * 2 + 2; ++q)
                    gld16(wsrc + q * 512 + ln * 8, wls + q * 1024);
                __syncthreads();                 // w[p+1] ready
            }
        }
    }

#pragma unroll
    for (int nb = 0; nb < 4; ++nb) {
        int co = wn * 64 + nb * 16 + lr;
        float bias = conv_b[co];
        float s = 0.f, ss = 0.f;
        float* op = out + (((size_t)b * C + co) * H + (y0 + wm)) * W + x0;
#pragma unroll
        for (int mb = 0; mb < 4; ++mb) {
            float4 o = make_float4(acc[mb][nb][0] + bias, acc[mb][nb][1] + bias,
                                   acc[mb][nb][2] + bias, acc[mb][nb][3] + bias);
            s  += (o.x + o.y) + (o.z + o.w);
            ss += (o.x * o.x + o.y * o.y) + (o.z * o.z + o.w * o.w);
            *(float4*)(op + mb * 16 + lg * 4) = o;
        }
        s += __shfl_xor(s, 1);  ss += __shfl_xor(ss, 1);    // co within group of 4
        s += __shfl_xor(s, 2);  ss += __shfl_xor(ss, 2);
        s += __shfl_xor(s, 16); ss += __shfl_xor(ss, 16);   // px quarters (lg)
        s += __shfl_xor(s, 32); ss += __shfl_xor(ss, 32);
        if (lg == 0 && (lr & 3) == 0) {
            int g = co >> 2;
            pst[wm][g * 2]     = s;
            pst[wm][g * 2 + 1] = ss;
        }
    }
    __syncthreads();
    if (t < 64)
        pb[(size_t)blk * 64 + t] = pst[0][t] + pst[1][t] + pst[2][t] + pst[3][t];
}

// ---------------------------------------------------------------------------
__global__ void k_stats2(const float* __restrict__ pb, float* __restrict__ st2) {
    __shared__ float red[512];
    int blk = blockIdx.x;            // b*32 + g
    int b = blk >> 5, g = blk & 31;
    int t = threadIdx.x;
    float s = 0.f, ss = 0.f;
    for (int j = t; j < 512; j += 256) {
        const float* p = pb + ((size_t)(b * 512 + j)) * 64 + g * 2;
        s += p[0]; ss += p[1];
    }
    red[t * 2] = s; red[t * 2 + 1] = ss;
    __syncthreads();
    for (int o = 128; o >= 1; o >>= 1) {
        if (t < o) {
            red[t * 2]     += red[(t + o) * 2];
            red[t * 2 + 1] += red[(t + o) * 2 + 1];
        }
        __syncthreads();
    }
    if (t == 0) {
        const float inv = 1.0f / 524288.0f;
        float mean = red[0] * inv;
        float var  = red[1] * inv - mean * mean;
        st2[blk * 2]     = mean;
        st2[blk * 2 + 1] = rsqrtf(var + 1e-6f);
    }
}

__global__ void k_norm(const float* __restrict__ st2, const float* __restrict__ gamma,
                       const float* __restrict__ beta, float* __restrict__ out) {
    const int N4 = B * C * H * W / 4;
    int stride = gridDim.x * 256;
    for (int i4 = blockIdx.x * 256 + threadIdx.x; i4 < N4; i4 += stride) {
        int i = i4 * 4;
        int c = (i >> 17) & 127;
        int b = i >> 24;
        int g = c >> 2;
        float mean = st2[(b * 32 + g) * 2];
        float rstd = st2[(b * 32 + g) * 2 + 1];
        float ga = gamma[c], be = beta[c];
        float4 v = *(float4*)(out + i);
        float n0 = (v.x - mean) * rstd * ga + be;
        float n1 = (v.y - mean) * rstd * ga + be;
        float n2 = (v.z - mean) * rstd * ga + be;
        float n3 = (v.w - mean) * rstd * ga + be;
        v.x = n0 / (1.0f + __expf(-n0));
        v.y = n1 / (1.0f + __expf(-n1));
        v.z = n2 / (1.0f + __expf(-n2));
        v.w = n3 / (1.0f + __expf(-n3));
        *(float4*)(out + i) = v;
    }
}

// ---------------------------------------------------------------------------
extern "C" void kernel_launch(void* const* d_in, const int* in_sizes, int n_in,
                              void* d_out, int out_size, void* d_ws, size_t ws_size,
                              hipStream_t stream) {
    const float* x      = (const float*)d_in[0];
    const float* v      = (const float*)d_in[1];
    const float* Wq     = (const float*)d_in[2];
    const float* Wk     = (const float*)d_in[3];
    const float* Wv     = (const float*)d_in[4];
    const float* Wo     = (const float*)d_in[5];
    const float* bo     = (const float*)d_in[6];
    const float* mask_w = (const float*)d_in[7];
    const float* conv_w = (const float*)d_in[8];
    const float* conv_b = (const float*)d_in[9];
    const float* gng    = (const float*)d_in[10];
    const float* gnb    = (const float*)d_in[11];

    float* out  = (float*)d_out;
    float* mout = out + B * C * H * W;
    // d_out's out-region is dead until k_convg writes it -> first 64 MB holds
    // the bf16 attn feature (consumed by k_cat strictly before k_convg).
    ushort* af16 = (ushort*)d_out;

    char*  wsb  = (char*)d_ws;
    ushort* catn  = (ushort*)(wsb + WS_CATN);
    ushort* kqc   = (ushort*)(wsb + WS_KQ);
    ushort* voc   = (ushort*)(wsb + WS_VOT);
    ushort* w9p   = (ushort*)(wsb + WS_W9);
    float*  bin   = (float*)(wsb + WS_BIN);
    float*  st2   = (float*)(wsb + WS_ST2);
    // pb (1024 blocks x 64 f32 = 256 KB) aliases kqc region (dead after k_attn).
    float*  pb    = (float*)(wsb + WS_KQ);

    k_binary <<<1,    256, 0, stream>>>(mask_w, bin);
    k_maskout<<<1024, 256, 0, stream>>>(bin, mout);
    k_kv     <<<B * NCOND, 256, 0, stream>>>(v, Wk, Wv, Wq, Wo, kqc, voc);
    k_w9p    <<<1152, 256, 0, stream>>>(conv_w, w9p);
    k_attn   <<<4096, 256, 0, stream>>>(x, kqc, voc, bo, af16);
    k_cat    <<<4096, 256, 0, stream>>>(x, af16, bin, catn);
    k_convg  <<<1024, 512, 0, stream>>>(catn, w9p, conv_b, out, pb);
    k_stats2 <<<64,   256, 0, stream>>>(pb, st2);
    k_norm   <<<2048, 256, 0, stream>>>(st2, gng, gnb, out);
}